// Round 1
// baseline (206.906 us; speedup 1.0000x reference)
//
#include <hip/hip_runtime.h>
#include <math.h>

#ifndef __has_builtin
#define __has_builtin(x) 0
#endif

#if __has_builtin(__builtin_amdgcn_rcpf)
#define FAST_RCP(x) __builtin_amdgcn_rcpf(x)
#else
#define FAST_RCP(x) (1.0f / (x))
#endif

#if __has_builtin(__builtin_amdgcn_exp2f)
#define FAST_EXP2(x) __builtin_amdgcn_exp2f(x)
#else
#define FAST_EXP2(x) exp2f(x)
#endif

typedef _Float16 half8 __attribute__((ext_vector_type(8)));
typedef _Float16 half2v __attribute__((ext_vector_type(2)));
typedef float f32x4 __attribute__((ext_vector_type(4)));
typedef float f32x2 __attribute__((ext_vector_type(2)));

constexpr int T_STEPS = 180;
constexpr int I_DIM   = 7;
constexpr int HDIM    = 64;
constexpr int BT      = 16;    // batch tile per block
constexpr int NCH     = 12;    // 12 chunks x 8 halfs = 96 K rows
constexpr int CH_HALF = BT * 8; // halfs per chunk slice (=128)

// Block = 512 threads = 8 waves; wave w owns row-tiles {2w, 2w+1}.
// Per step GEMM: gates[256 x 16] = W_aug[256 x 96(f16)] . v[96 x 16(f16)],
//   v = [x_t(7), 1, h_{t-1}(64), pad(24 zeros)].
// B operand stored CHUNK-MAJOR: Bbuf[buf][c][n][8], granule (c,n) = 16B at
// offset (c*16+n)*16B. A wave's b128 fragment read for k-chunk kc covers
// granules {64*kc + 16*q + n15} = 64 CONSECUTIVE granules -> contiguous
// 1024B, LDS-bank-conflict-free (fixes the 8-way conflicts of the row-major
// stride-208B layout). h writes: dword (1+w)*64 + 4*n15 + q -> 2-way (free).
// x is pre-staged ONCE into LDS (f16, fragment layout, bias folded at half 7);
// the main loop has ZERO vmem ops, so the vmcnt(0) drain at each barrier is
// free. Per step, 16 lanes of wave 7 copy xstage[t+1] (256B) into the next
// buffer's chunk 0 (disjoint from h chunks 1..8; pad chunks 9..11 stay zero).
// A rows packed UNIT-MAJOR with ADJACENT-unit remap (unchanged):
//   tile rt=2w+pt, row-quad rq, gate g -> param row g*64 + (8w + 2*rq + pt)
// so lane (q,n15)'s acc regs = i,f,g,o of unit 8w+2q+pt; the thread's two
// cells are units {8w+2q, 8w+2q+1}: h stored as ONE packed b32 write.
// Activation scales pre-folded into weights; cell math shared-denominator:
// 5 exp2 + 2 rcp per cell.
__global__ __launch_bounds__(512, 4) void lstm_mfma_kernel(
    const float* __restrict__ x,
    const float* __restrict__ W_ih,
    const float* __restrict__ W_hh,
    const float* __restrict__ b_ih,
    const float* __restrict__ b_hh,
    const float* __restrict__ W_fc,
    const float* __restrict__ b_fc,
    float* __restrict__ out) {
    __shared__ alignas(16) _Float16 Bbuf[2][NCH][BT][8];
    __shared__ alignas(16) _Float16 xstage[T_STEPS + 1][BT][8];
    __shared__ alignas(16) float hlds[BT][HDIM + 4];   // fp32 h_T for epilogue

    const int tid  = (int)threadIdx.x;
    const int w    = tid >> 6;    // wave 0..7
    const int lane = tid & 63;
    const int q    = lane >> 4;   // quad 0..3
    const int n15  = lane & 15;   // batch col within tile
    const long bbase = (long)blockIdx.x * BT;

    // ---- A fragments, scale-folded, in registers for all 180 steps ----
    half8 afrag[2][3];
#pragma unroll
    for (int pt = 0; pt < 2; ++pt) {
        const int rq   = n15 >> 2;            // row-quad of this packed row
        const int gate = n15 & 3;
        const int unit = 8 * w + 2 * rq + pt; // adjacent-unit remap
        const int grow = gate * HDIM + unit;  // row in PyTorch [4H, *] params
        const float scl = (gate == 2) ? 2.88539008177792681472f
                                      : -1.44269504088896340736f;
#pragma unroll
        for (int kc = 0; kc < 3; ++kc) {
#pragma unroll
            for (int j = 0; j < 8; ++j) {
                const int k = kc * 32 + q * 8 + j;
                float v;
                if (k < I_DIM)            v = W_ih[grow * I_DIM + k];
                else if (k == I_DIM)      v = b_ih[grow] + b_hh[grow];
                else if (k < 8 + HDIM)    v = W_hh[grow * HDIM + (k - 8)];
                else                      v = 0.0f;
                afrag[pt][kc][j] = (_Float16)(scl * v);
            }
        }
    }

    // ---- prologue: stage all x into LDS (f16, fragment layout) ----
    // xstage[t][n][0..6] = x_t, [7] = 1.0 (bias multiplier).
    for (int idx = tid; idx < BT * T_STEPS * I_DIM; idx += 512) {
        const int n = idx / (T_STEPS * I_DIM);
        const int r = idx - n * (T_STEPS * I_DIM);
        const int t = r / I_DIM, i = r - t * I_DIM;
        xstage[t][n][i] = (_Float16)x[(bbase + n) * (T_STEPS * I_DIM) + r];
    }
    for (int idx = tid; idx < T_STEPS * BT; idx += 512)
        xstage[idx >> 4][idx & 15][7] = (_Float16)1.0f;
    // zero both B buffers: h chunks (h_0 = 0) and pad chunks (must not be NaN)
    for (int idx = tid; idx < 2 * NCH * CH_HALF; idx += 512)
        ((_Float16*)Bbuf)[idx] = (_Float16)0.0f;
    __syncthreads();
    if (tid < BT)   // chunk 0 of buf0 = x_0 + bias
        *(half8*)&Bbuf[0][0][tid][0] = *(const half8*)&xstage[0][tid][0];
    __syncthreads();

    // cell ownership: units u0 = 8w+2q, u0+1 (adjacent)
    const int u0 = 8 * w + 2 * q;

    // hoisted LDS pointers (loop-invariant). Fragment reads: chunk q (+4,+8).
    const _Float16* const rb0 = &Bbuf[0][q][n15][0];
    const _Float16* const rb1 = &Bbuf[1][q][n15][0];
    half2v* const hw0 = (half2v*)&Bbuf[0][1 + w][n15][2 * q];
    half2v* const hw1 = (half2v*)&Bbuf[1][1 + w][n15][2 * q];

    // x copy lanes: 16 lanes of wave 7 move xstage[t+1] -> next buf chunk 0.
    // (Last step copies xstage[180] = in-bounds garbage into a never-read
    // buffer slot; harmless by construction.)
    const bool cp = (w == 7 && q == 0);
    const _Float16* cpr = &xstage[1][n15][0];
    _Float16* const cpw0 = &Bbuf[0][0][n15][0];
    _Float16* const cpw1 = &Bbuf[1][0][n15][0];

    float c0 = 0.0f, c1 = 0.0f, h0 = 0.0f, h1 = 0.0f;

    // cell: acc = {i',f',g',o'} exp2-ready.  A=2^i', F=2^f', E=2^g', O=2^o'
    //   c' = (c*P + (E-1)*Q) * rcp(P*Q),  P=(1+A)(E+1), Q=1+F
    //   h  = (C-1) * rcp((1+O)(C+1)),     C=2^(k*c') clamped
#define LSTM_CELL(ACC, CREG, HREG)                                             \
    {                                                                          \
        const float A = FAST_EXP2(ACC[0]);                                     \
        const float F = FAST_EXP2(ACC[1]);                                     \
        const float E = FAST_EXP2(ACC[2]);                                     \
        const float P = (1.0f + A) * (E + 1.0f);                               \
        const float Q = 1.0f + F;                                              \
        const float R = FAST_RCP(P * Q);                                       \
        CREG = (CREG * P + (E - 1.0f) * Q) * R;                                \
        const float O = FAST_EXP2(ACC[3]);                                     \
        float cs = 2.88539008177792681472f * CREG;                             \
        cs = fminf(fmaxf(cs, -80.0f), 80.0f);                                  \
        const float C = FAST_EXP2(cs);                                         \
        HREG = (C - 1.0f) * FAST_RCP((1.0f + O) * (C + 1.0f));                 \
    }

#define LSTM_STEP(RB, HW, CPW)                                                 \
    {                                                                          \
        const half8 bf0 = *(const half8*)(RB);                                 \
        const half8 bf1 = *(const half8*)((RB) + 4 * CH_HALF);                 \
        const half8 bf2 = *(const half8*)((RB) + 8 * CH_HALF);                 \
        if (cp) {                                                              \
            *(half8*)(CPW) = *(const half8*)cpr;                               \
            cpr += CH_HALF;                                                    \
        }                                                                      \
        f32x4 acc0 = {0.f, 0.f, 0.f, 0.f};                                     \
        f32x4 acc1 = {0.f, 0.f, 0.f, 0.f};                                     \
        acc0 = __builtin_amdgcn_mfma_f32_16x16x32_f16(afrag[0][0], bf0, acc0, 0, 0, 0); \
        acc1 = __builtin_amdgcn_mfma_f32_16x16x32_f16(afrag[1][0], bf0, acc1, 0, 0, 0); \
        acc0 = __builtin_amdgcn_mfma_f32_16x16x32_f16(afrag[0][1], bf1, acc0, 0, 0, 0); \
        acc1 = __builtin_amdgcn_mfma_f32_16x16x32_f16(afrag[1][1], bf1, acc1, 0, 0, 0); \
        acc0 = __builtin_amdgcn_mfma_f32_16x16x32_f16(afrag[0][2], bf2, acc0, 0, 0, 0); \
        acc1 = __builtin_amdgcn_mfma_f32_16x16x32_f16(afrag[1][2], bf2, acc1, 0, 0, 0); \
        LSTM_CELL(acc0, c0, h0)                                                \
        LSTM_CELL(acc1, c1, h1)                                                \
        *(HW) = (half2v){(_Float16)h0, (_Float16)h1};                          \
        __syncthreads();                                                       \
    }

    for (int t = 0; t < T_STEPS; t += 2) {
        LSTM_STEP(rb0, hw1, cpw1)       // read buf0, write h+x into buf1
        LSTM_STEP(rb1, hw0, cpw0)       // read buf1, write h+x into buf0
    }
#undef LSTM_STEP
#undef LSTM_CELL

    // ---- epilogue: out[b][j] = b_fc[j] + sum_u h[b][u] * W_fc[j][u] ----
    *(f32x2*)&hlds[n15][u0] = (f32x2){h0, h1};
    __syncthreads();
    if (tid < 256) {
        const int b = tid >> 4, j = tid & 15;
        float s = b_fc[j];
#pragma unroll 8
        for (int u = 0; u < HDIM; ++u)
            s += hlds[b][u] * W_fc[j * HDIM + u];
        out[(bbase + b) * 16 + j] = s;
    }
}

extern "C" void kernel_launch(void* const* d_in, const int* in_sizes, int n_in,
                              void* d_out, int out_size, void* d_ws, size_t ws_size,
                              hipStream_t stream) {
    const float* x    = (const float*)d_in[0];
    const float* W_ih = (const float*)d_in[1];
    const float* W_hh = (const float*)d_in[2];
    const float* b_ih = (const float*)d_in[3];
    const float* b_hh = (const float*)d_in[4];
    const float* W_fc = (const float*)d_in[5];
    const float* b_fc = (const float*)d_in[6];
    float* out = (float*)d_out;

    const int B = in_sizes[0] / (T_STEPS * I_DIM);  // 8192
    const int grid = B / BT;                         // 512 blocks

    lstm_mfma_kernel<<<grid, 512, 0, stream>>>(x, W_ih, W_hh, b_ih, b_hh,
                                               W_fc, b_fc, out);
}

// Round 2
// 196.784 us; speedup vs baseline: 1.0514x; 1.0514x over previous
//
#include <hip/hip_runtime.h>
#include <math.h>

#ifndef __has_builtin
#define __has_builtin(x) 0
#endif

#if __has_builtin(__builtin_amdgcn_rcpf)
#define FAST_RCP(x) __builtin_amdgcn_rcpf(x)
#else
#define FAST_RCP(x) (1.0f / (x))
#endif

#if __has_builtin(__builtin_amdgcn_exp2f)
#define FAST_EXP2(x) __builtin_amdgcn_exp2f(x)
#else
#define FAST_EXP2(x) exp2f(x)
#endif

typedef _Float16 half8 __attribute__((ext_vector_type(8)));
typedef _Float16 half2v __attribute__((ext_vector_type(2)));
typedef float f32x4 __attribute__((ext_vector_type(4)));
typedef float f32x2 __attribute__((ext_vector_type(2)));

constexpr int T_STEPS = 180;
constexpr int I_DIM   = 7;
constexpr int HDIM    = 64;
constexpr int BT      = 16;     // batch tile per block
constexpr int NCH     = 12;     // 12 chunks x 8 halfs = 96 K rows
constexpr int CH_HALF = BT * 8; // halfs per chunk slice (=128)
constexpr int XSTR    = 136;    // halfs per xstage t-slice: 17 granules (272B)
                                // (16 data granules + 1 pad granule so the
                                //  t-stride is NOT bank-aligned: fixes ~16-way
                                //  conflicts in the prologue staging writes)

// Block = 512 threads = 8 waves; wave w owns row-tiles {2w, 2w+1}.
// Per step GEMM: gates[256 x 16] = W_aug[256 x 96(f16)] . v[96 x 16(f16)],
//   v = [x_t(7), 1, h_{t-1}(64), pad(24 zeros)].
// B operand CHUNK-MAJOR: chunk c holds k in [8c, 8c+8); granule (c,n) = 16B.
// Fragment read for k-chunk kc: lane (q,n15) reads chunk 4*kc+q, row n15 ->
// each consecutive-8-lane group covers one contiguous 128B range ->
// LDS-bank-conflict-free ds_read_b128 (validated in R1: conflicts 10.3M->2.9M).
// x feed: NO per-step copy (R1's serial ds_read->ds_write chain on wave 7 was
// a +15-20us barrier-path regression). Instead, the bf0 base pointer is
// LANE-BLENDED: q==0 lanes (k=0..7 = x+bias) read xstage[t] DIRECTLY
// (advancing 2 slices/iteration); q>=1 lanes stay on their fixed Bbuf chunk.
// Conflict-freeness preserved (lanes 0..7 read xstage[t][0..127B]). Bbuf
// chunk 0 is never touched in the loop; the loop has ZERO vmem ops and no
// LDS->LDS traffic -- fully wave-symmetric.
// h writes: dword (1+w)*64 + 4*n15 + q -> 2-way (free).
// A rows packed UNIT-MAJOR with ADJACENT-unit remap (unchanged):
//   tile rt=2w+pt, row-quad rq, gate g -> param row g*64 + (8w + 2*rq + pt)
// so lane (q,n15)'s acc regs = i,f,g,o of unit 8w+2q+pt; the thread's two
// cells are units {8w+2q, 8w+2q+1}: h stored as ONE packed b32 write.
// Activation scales pre-folded into weights; cell math shared-denominator:
// 5 exp2 + 2 rcp per cell.
__global__ __launch_bounds__(512, 4) void lstm_mfma_kernel(
    const float* __restrict__ x,
    const float* __restrict__ W_ih,
    const float* __restrict__ W_hh,
    const float* __restrict__ b_ih,
    const float* __restrict__ b_hh,
    const float* __restrict__ W_fc,
    const float* __restrict__ b_fc,
    float* __restrict__ out) {
    __shared__ alignas(16) _Float16 Bbuf[2][NCH][BT][8];
    __shared__ alignas(16) _Float16 xstage[T_STEPS * XSTR];
    __shared__ alignas(16) float hlds[BT][HDIM + 4];   // fp32 h_T for epilogue

    const int tid  = (int)threadIdx.x;
    const int w    = tid >> 6;    // wave 0..7
    const int lane = tid & 63;
    const int q    = lane >> 4;   // quad 0..3
    const int n15  = lane & 15;   // batch col within tile
    const long bbase = (long)blockIdx.x * BT;

    // ---- A fragments, scale-folded, in registers for all 180 steps ----
    half8 afrag[2][3];
#pragma unroll
    for (int pt = 0; pt < 2; ++pt) {
        const int rq   = n15 >> 2;            // row-quad of this packed row
        const int gate = n15 & 3;
        const int unit = 8 * w + 2 * rq + pt; // adjacent-unit remap
        const int grow = gate * HDIM + unit;  // row in PyTorch [4H, *] params
        const float scl = (gate == 2) ? 2.88539008177792681472f
                                      : -1.44269504088896340736f;
#pragma unroll
        for (int kc = 0; kc < 3; ++kc) {
#pragma unroll
            for (int j = 0; j < 8; ++j) {
                const int k = kc * 32 + q * 8 + j;
                float v;
                if (k < I_DIM)            v = W_ih[grow * I_DIM + k];
                else if (k == I_DIM)      v = b_ih[grow] + b_hh[grow];
                else if (k < 8 + HDIM)    v = W_hh[grow * HDIM + (k - 8)];
                else                      v = 0.0f;
                afrag[pt][kc][j] = (_Float16)(scl * v);
            }
        }
    }

    // ---- prologue: stage all x into LDS (f16, fragment layout) ----
    // xstage slice t: [n*8 + i] = x_t[n][i] for i<7, [n*8+7] = 1.0 (bias col).
    for (int idx = tid; idx < BT * T_STEPS * I_DIM; idx += 512) {
        const int n = idx / (T_STEPS * I_DIM);
        const int r = idx - n * (T_STEPS * I_DIM);
        const int t = r / I_DIM, i = r - t * I_DIM;
        xstage[t * XSTR + n * 8 + i] =
            (_Float16)x[(bbase + n) * (T_STEPS * I_DIM) + r];
    }
    for (int idx = tid; idx < T_STEPS * BT; idx += 512)
        xstage[(idx >> 4) * XSTR + (idx & 15) * 8 + 7] = (_Float16)1.0f;
    // zero both B buffers: h chunks (h_0 = 0) and pad chunks (must not be NaN)
    for (int idx = tid; idx < 2 * NCH * CH_HALF; idx += 512)
        ((_Float16*)Bbuf)[idx] = (_Float16)0.0f;
    __syncthreads();

    // cell ownership: units u0 = 8w+2q, u0+1 (adjacent)
    const int u0 = 8 * w + 2 * q;

    // hoisted LDS pointers. Fragment reads: bf0 from blended xb (q==0 lanes
    // walk xstage, q>=1 lanes fixed Bbuf chunk q); bf1/bf2 at chunk 4+q, 8+q.
    const _Float16* const rb0 = &Bbuf[0][q][n15][0];
    const _Float16* const rb1 = &Bbuf[1][q][n15][0];
    const _Float16* xb0 = (q == 0) ? &xstage[0 * XSTR + n15 * 8] : rb0;
    const _Float16* xb1 = (q == 0) ? &xstage[1 * XSTR + n15 * 8] : rb1;
    const int xadv = (q == 0) ? 2 * XSTR : 0;
    half2v* const hw0 = (half2v*)&Bbuf[0][1 + w][n15][2 * q];
    half2v* const hw1 = (half2v*)&Bbuf[1][1 + w][n15][2 * q];

    float c0 = 0.0f, c1 = 0.0f, h0 = 0.0f, h1 = 0.0f;

    // cell: acc = {i',f',g',o'} exp2-ready.  A=2^i', F=2^f', E=2^g', O=2^o'
    //   c' = (c*P + (E-1)*Q) * rcp(P*Q),  P=(1+A)(E+1), Q=1+F
    //   h  = (C-1) * rcp((1+O)(C+1)),     C=2^(k*c') clamped
#define LSTM_CELL(ACC, CREG, HREG)                                             \
    {                                                                          \
        const float A = FAST_EXP2(ACC[0]);                                     \
        const float F = FAST_EXP2(ACC[1]);                                     \
        const float E = FAST_EXP2(ACC[2]);                                     \
        const float P = (1.0f + A) * (E + 1.0f);                               \
        const float Q = 1.0f + F;                                              \
        const float R = FAST_RCP(P * Q);                                       \
        CREG = (CREG * P + (E - 1.0f) * Q) * R;                                \
        const float O = FAST_EXP2(ACC[3]);                                     \
        float cs = 2.88539008177792681472f * CREG;                             \
        cs = fminf(fmaxf(cs, -80.0f), 80.0f);                                  \
        const float C = FAST_EXP2(cs);                                         \
        HREG = (C - 1.0f) * FAST_RCP((1.0f + O) * (C + 1.0f));                 \
    }

#define LSTM_STEP(RB, XB, HW)                                                  \
    {                                                                          \
        const half8 bf0 = *(const half8*)(XB);                                 \
        const half8 bf1 = *(const half8*)((RB) + 4 * CH_HALF);                 \
        const half8 bf2 = *(const half8*)((RB) + 8 * CH_HALF);                 \
        f32x4 acc0 = {0.f, 0.f, 0.f, 0.f};                                     \
        f32x4 acc1 = {0.f, 0.f, 0.f, 0.f};                                     \
        acc0 = __builtin_amdgcn_mfma_f32_16x16x32_f16(afrag[0][0], bf0, acc0, 0, 0, 0); \
        acc1 = __builtin_amdgcn_mfma_f32_16x16x32_f16(afrag[1][0], bf0, acc1, 0, 0, 0); \
        acc0 = __builtin_amdgcn_mfma_f32_16x16x32_f16(afrag[0][1], bf1, acc0, 0, 0, 0); \
        acc1 = __builtin_amdgcn_mfma_f32_16x16x32_f16(afrag[1][1], bf1, acc1, 0, 0, 0); \
        acc0 = __builtin_amdgcn_mfma_f32_16x16x32_f16(afrag[0][2], bf2, acc0, 0, 0, 0); \
        acc1 = __builtin_amdgcn_mfma_f32_16x16x32_f16(afrag[1][2], bf2, acc1, 0, 0, 0); \
        LSTM_CELL(acc0, c0, h0)                                                \
        LSTM_CELL(acc1, c1, h1)                                                \
        *(HW) = (half2v){(_Float16)h0, (_Float16)h1};                          \
        __syncthreads();                                                       \
    }

    for (int t = 0; t < T_STEPS; t += 2) {
        LSTM_STEP(rb0, xb0, hw1)       // read buf0 (+ xstage[t]),   write buf1
        LSTM_STEP(rb1, xb1, hw0)       // read buf1 (+ xstage[t+1]), write buf0
        xb0 += xadv;
        xb1 += xadv;
    }
#undef LSTM_STEP
#undef LSTM_CELL

    // ---- epilogue: out[b][j] = b_fc[j] + sum_u h[b][u] * W_fc[j][u] ----
    *(f32x2*)&hlds[n15][u0] = (f32x2){h0, h1};
    __syncthreads();
    if (tid < 256) {
        const int b = tid >> 4, j = tid & 15;
        float s = b_fc[j];
#pragma unroll 8
        for (int u = 0; u < HDIM; ++u)
            s += hlds[b][u] * W_fc[j * HDIM + u];
        out[(bbase + b) * 16 + j] = s;
    }
}

extern "C" void kernel_launch(void* const* d_in, const int* in_sizes, int n_in,
                              void* d_out, int out_size, void* d_ws, size_t ws_size,
                              hipStream_t stream) {
    const float* x    = (const float*)d_in[0];
    const float* W_ih = (const float*)d_in[1];
    const float* W_hh = (const float*)d_in[2];
    const float* b_ih = (const float*)d_in[3];
    const float* b_hh = (const float*)d_in[4];
    const float* W_fc = (const float*)d_in[5];
    const float* b_fc = (const float*)d_in[6];
    float* out = (float*)d_out;

    const int B = in_sizes[0] / (T_STEPS * I_DIM);  // 8192
    const int grid = B / BT;                         // 512 blocks

    lstm_mfma_kernel<<<grid, 512, 0, stream>>>(x, W_ih, W_hh, b_ih, b_hh,
                                               W_fc, b_fc, out);
}

// Round 3
// 191.725 us; speedup vs baseline: 1.0792x; 1.0264x over previous
//
#include <hip/hip_runtime.h>
#include <math.h>

#ifndef __has_builtin
#define __has_builtin(x) 0
#endif

#if __has_builtin(__builtin_amdgcn_rcpf)
#define FAST_RCP(x) __builtin_amdgcn_rcpf(x)
#else
#define FAST_RCP(x) (1.0f / (x))
#endif

#if __has_builtin(__builtin_amdgcn_exp2f)
#define FAST_EXP2(x) __builtin_amdgcn_exp2f(x)
#else
#define FAST_EXP2(x) exp2f(x)
#endif

typedef _Float16 half8 __attribute__((ext_vector_type(8)));
typedef _Float16 half2v __attribute__((ext_vector_type(2)));
typedef float f32x4 __attribute__((ext_vector_type(4)));
typedef float f32x2 __attribute__((ext_vector_type(2)));

constexpr int T_STEPS = 180;
constexpr int I_DIM   = 7;
constexpr int HDIM    = 64;
constexpr int BT      = 16;     // batch tile per block
constexpr int NCH     = 12;     // 12 chunks x 8 halfs = 96 K rows
constexpr int CH_HALF = BT * 8; // halfs per chunk slice (=128)
constexpr int XSTR    = 136;    // halfs per xstage t-slice: 17 granules (272B)

// Block = 512 threads = 8 waves; wave w owns row-tiles {2w, 2w+1}.
// Per step GEMM: gates[256 x 16] = W_aug[256 x 96(f16)] . v[96 x 16(f16)],
//   v = [x_t(7), 1, h_{t-1}(64), pad(24 zeros)].
// B operand CHUNK-MAJOR (conflict-free ds_read_b128, validated R1/R2).
// x feed: bf0 base pointer LANE-BLENDED into the pre-staged xstage (q==0
// lanes walk xstage; q>=1 lanes read h chunks 1..3). Zero loop vmem.
// ---- R3: GATE-PAIR accumulator remap + packed dual-FP32 cell math ----
// A-row remap: tile pt, row r -> param row gate*64 + unit with
//   gate = 2*pt + ((r>>1)&1),  unit = 8w + 2*(r>>2) + (r&1)
// so lane (q,n15) gets acc0 = {i(u0), i(u0+1), f(u0), f(u0+1)},
//                     acc1 = {g(u0), g(u0+1), o(u0), o(u0+1)}, u0 = 8w+2q.
// Every gate is an ALIGNED VGPR PAIR across the thread's two cells straight
// out of the MFMA -> the whole cell chain runs as v_pk_*_f32 packed ops
// (~15 pk instead of ~36 scalar VALU); exp2/rcp stay scalar per component.
// Cell ownership (units u0,u0+1) and the packed b32 h-write are unchanged.
// Activation scales pre-folded into weights; shared-denominator cell:
// 5 exp2 + 2 rcp per cell.
__global__ __launch_bounds__(512, 4) void lstm_mfma_kernel(
    const float* __restrict__ x,
    const float* __restrict__ W_ih,
    const float* __restrict__ W_hh,
    const float* __restrict__ b_ih,
    const float* __restrict__ b_hh,
    const float* __restrict__ W_fc,
    const float* __restrict__ b_fc,
    float* __restrict__ out) {
    __shared__ alignas(16) _Float16 Bbuf[2][NCH][BT][8];
    __shared__ alignas(16) _Float16 xstage[T_STEPS * XSTR];
    __shared__ alignas(16) float hlds[BT][HDIM + 4];   // fp32 h_T for epilogue

    const int tid  = (int)threadIdx.x;
    const int w    = tid >> 6;    // wave 0..7
    const int lane = tid & 63;
    const int q    = lane >> 4;   // quad 0..3
    const int n15  = lane & 15;   // batch col within tile
    const long bbase = (long)blockIdx.x * BT;

    // ---- A fragments, scale-folded, gate-pair remap ----
    half8 afrag[2][3];
#pragma unroll
    for (int pt = 0; pt < 2; ++pt) {
        // A-row of this lane is n15; remap to (gate, unit):
        const int gate = 2 * pt + ((n15 >> 1) & 1);
        const int unit = 8 * w + 2 * (n15 >> 2) + (n15 & 1);
        const int grow = gate * HDIM + unit;  // row in PyTorch [4H, *] params
        const float scl = (gate == 2) ? 2.88539008177792681472f
                                      : -1.44269504088896340736f;
#pragma unroll
        for (int kc = 0; kc < 3; ++kc) {
#pragma unroll
            for (int j = 0; j < 8; ++j) {
                const int k = kc * 32 + q * 8 + j;
                float v;
                if (k < I_DIM)            v = W_ih[grow * I_DIM + k];
                else if (k == I_DIM)      v = b_ih[grow] + b_hh[grow];
                else if (k < 8 + HDIM)    v = W_hh[grow * HDIM + (k - 8)];
                else                      v = 0.0f;
                afrag[pt][kc][j] = (_Float16)(scl * v);
            }
        }
    }

    // ---- prologue: stage all x into LDS (f16, fragment layout) ----
    for (int idx = tid; idx < BT * T_STEPS * I_DIM; idx += 512) {
        const int n = idx / (T_STEPS * I_DIM);
        const int r = idx - n * (T_STEPS * I_DIM);
        const int t = r / I_DIM, i = r - t * I_DIM;
        xstage[t * XSTR + n * 8 + i] =
            (_Float16)x[(bbase + n) * (T_STEPS * I_DIM) + r];
    }
    for (int idx = tid; idx < T_STEPS * BT; idx += 512)
        xstage[(idx >> 4) * XSTR + (idx & 15) * 8 + 7] = (_Float16)1.0f;
    for (int idx = tid; idx < 2 * NCH * CH_HALF; idx += 512)
        ((_Float16*)Bbuf)[idx] = (_Float16)0.0f;
    __syncthreads();

    // cell ownership: units u0 = 8w+2q, u0+1 (adjacent)
    const int u0 = 8 * w + 2 * q;

    // hoisted LDS pointers (bf0 blended: q==0 walks xstage)
    const _Float16* const rb0 = &Bbuf[0][q][n15][0];
    const _Float16* const rb1 = &Bbuf[1][q][n15][0];
    const _Float16* xb0 = (q == 0) ? &xstage[0 * XSTR + n15 * 8] : rb0;
    const _Float16* xb1 = (q == 0) ? &xstage[1 * XSTR + n15 * 8] : rb1;
    const int xadv = (q == 0) ? 2 * XSTR : 0;
    half2v* const hw0 = (half2v*)&Bbuf[0][1 + w][n15][2 * q];
    half2v* const hw1 = (half2v*)&Bbuf[1][1 + w][n15][2 * q];

    f32x2 cp = {0.0f, 0.0f};
    f32x2 hp = {0.0f, 0.0f};
    const f32x4 zq = {0.0f, 0.0f, 0.0f, 0.0f};   // hoisted MFMA C=0 operand

    // Packed cell: acc0={i0,i1,f0,f1}, acc1={g0,g1,o0,o1} (exp2-ready).
    //   A=2^i', F=2^f', E=2^g', O=2^o'  (pairwise across the 2 cells)
    //   c' = (c*P + (E-1)*Q) * rcp(P*Q),  P=(1+A)(E+1), Q=1+F
    //   h  = (C-1) * rcp((1+O)(C+1)),     C=2^(k*c') clamped
#define LSTM_CELL2(A0, A1)                                                     \
    {                                                                          \
        f32x2 Ap, Fp, Ep, Op, Rp, Cp, rD;                                      \
        Ap[0] = FAST_EXP2(A0[0]); Ap[1] = FAST_EXP2(A0[1]);                    \
        Fp[0] = FAST_EXP2(A0[2]); Fp[1] = FAST_EXP2(A0[3]);                    \
        Ep[0] = FAST_EXP2(A1[0]); Ep[1] = FAST_EXP2(A1[1]);                    \
        const f32x2 Pp = (Ap + 1.0f) * (Ep + 1.0f);                            \
        const f32x2 Qp = Fp + 1.0f;                                            \
        const f32x2 PQ = Pp * Qp;                                              \
        Rp[0] = FAST_RCP(PQ[0]); Rp[1] = FAST_RCP(PQ[1]);                      \
        cp = (cp * Pp + (Ep - 1.0f) * Qp) * Rp;                                \
        Op[0] = FAST_EXP2(A1[2]); Op[1] = FAST_EXP2(A1[3]);                    \
        f32x2 cs = cp * 2.88539008177792681472f;                               \
        cs[0] = fminf(fmaxf(cs[0], -80.0f), 80.0f);                            \
        cs[1] = fminf(fmaxf(cs[1], -80.0f), 80.0f);                            \
        Cp[0] = FAST_EXP2(cs[0]); Cp[1] = FAST_EXP2(cs[1]);                    \
        const f32x2 Dp = (Op + 1.0f) * (Cp + 1.0f);                            \
        rD[0] = FAST_RCP(Dp[0]); rD[1] = FAST_RCP(Dp[1]);                      \
        hp = (Cp - 1.0f) * rD;                                                 \
    }

#define LSTM_STEP(RB, XB, HW)                                                  \
    {                                                                          \
        const half8 bf0 = *(const half8*)(XB);                                 \
        const half8 bf1 = *(const half8*)((RB) + 4 * CH_HALF);                 \
        const half8 bf2 = *(const half8*)((RB) + 8 * CH_HALF);                 \
        f32x4 acc0 = __builtin_amdgcn_mfma_f32_16x16x32_f16(afrag[0][0], bf0, zq, 0, 0, 0); \
        f32x4 acc1 = __builtin_amdgcn_mfma_f32_16x16x32_f16(afrag[1][0], bf0, zq, 0, 0, 0); \
        acc0 = __builtin_amdgcn_mfma_f32_16x16x32_f16(afrag[0][1], bf1, acc0, 0, 0, 0); \
        acc1 = __builtin_amdgcn_mfma_f32_16x16x32_f16(afrag[1][1], bf1, acc1, 0, 0, 0); \
        acc0 = __builtin_amdgcn_mfma_f32_16x16x32_f16(afrag[0][2], bf2, acc0, 0, 0, 0); \
        acc1 = __builtin_amdgcn_mfma_f32_16x16x32_f16(afrag[1][2], bf2, acc1, 0, 0, 0); \
        LSTM_CELL2(acc0, acc1)                                                 \
        *(HW) = (half2v){(_Float16)hp[0], (_Float16)hp[1]};                    \
        __syncthreads();                                                       \
    }

    for (int t = 0; t < T_STEPS; t += 2) {
        LSTM_STEP(rb0, xb0, hw1)       // read buf0 (+ xstage[t]),   write buf1
        LSTM_STEP(rb1, xb1, hw0)       // read buf1 (+ xstage[t+1]), write buf0
        xb0 += xadv;
        xb1 += xadv;
    }
#undef LSTM_STEP
#undef LSTM_CELL2

    // ---- epilogue: out[b][j] = b_fc[j] + sum_u h[b][u] * W_fc[j][u] ----
    *(f32x2*)&hlds[n15][u0] = hp;
    __syncthreads();
    if (tid < 256) {
        const int b = tid >> 4, j = tid & 15;
        float s = b_fc[j];
#pragma unroll 8
        for (int u = 0; u < HDIM; ++u)
            s += hlds[b][u] * W_fc[j * HDIM + u];
        out[(bbase + b) * 16 + j] = s;
    }
}

extern "C" void kernel_launch(void* const* d_in, const int* in_sizes, int n_in,
                              void* d_out, int out_size, void* d_ws, size_t ws_size,
                              hipStream_t stream) {
    const float* x    = (const float*)d_in[0];
    const float* W_ih = (const float*)d_in[1];
    const float* W_hh = (const float*)d_in[2];
    const float* b_ih = (const float*)d_in[3];
    const float* b_hh = (const float*)d_in[4];
    const float* W_fc = (const float*)d_in[5];
    const float* b_fc = (const float*)d_in[6];
    float* out = (float*)d_out;

    const int B = in_sizes[0] / (T_STEPS * I_DIM);  // 8192
    const int grid = B / BT;                         // 512 blocks

    lstm_mfma_kernel<<<grid, 512, 0, stream>>>(x, W_ih, W_hh, b_ih, b_hh,
                                               W_fc, b_fc, out);
}